// Round 15
// baseline (152.173 us; speedup 1.0000x reference)
//
#include <hip/hip_runtime.h>
#include <hip/hip_bf16.h>
#include <cstdint>

#define NEGV (-10000.0f)

typedef short bf16x8 __attribute__((ext_vector_type(8)));
typedef short bf16x4 __attribute__((ext_vector_type(4)));
typedef float f32x4 __attribute__((ext_vector_type(4)));

__device__ __forceinline__ short f2bf(float f) {
  union { float f; uint32_t u; } v; v.f = f;
  uint32_t u = v.u + 0x7fffu + ((v.u >> 16) & 1u);
  return (short)(u >> 16);
}
__device__ __forceinline__ float b2f(short s) {
  union { uint32_t u; float f; } v; v.u = ((uint32_t)(uint16_t)s) << 16;
  return v.f;
}
__device__ __forceinline__ uint32_t pk2(float lo, float hi) {
  union { __hip_bfloat162 h2; uint32_t u; } cv;
  cv.h2.x = __float2bfloat16(lo);
  cv.h2.y = __float2bfloat16(hi);
  return cv.u;
}

// LDS-only barrier: no vmcnt drain; ring prefetch loads survive barriers.
__device__ __forceinline__ void bar() {
  __builtin_amdgcn_sched_barrier(0);
  asm volatile("s_waitcnt lgkmcnt(0)" ::: "memory");
  __builtin_amdgcn_s_barrier();
  __builtin_amdgcn_sched_barrier(0);
}

// ---------------- P1: weight combine + bf16 casts ----------------
__global__ void prep_weights(const float* __restrict__ W1, const float* __restrict__ W2,
                             short* __restrict__ Wk, short* __restrict__ Wd,
                             short* __restrict__ W2b) {
  int idx = blockIdx.x * 256 + threadIdx.x;
  if (idx < 32768) {
    int h = idx >> 7, d = idx & 127;
    Wk[idx] = f2bf(W1[h * 512 + 128 + d] - W1[h * 512 + 256 + d]);
  } else if (idx < 65536) {
    int i = idx - 32768;
    int h = i >> 7, d = i & 127;
    Wd[i] = f2bf(W1[h * 512 + 384 + d]);
  } else {
    int i = idx - 65536;
    W2b[i] = f2bf(W2[i]);
  }
}

// ---------------- P2: U[b][h] = b1[h] + sum_d (W1[h][d]+W1[h][256+d]) * q[b][d] ----
__global__ void prep_u(const float* __restrict__ query, const float* __restrict__ W1,
                       const float* __restrict__ b1, float* __restrict__ U) {
  __shared__ float q8[8][128];
  int tid = threadIdx.x;
  int b0 = blockIdx.x * 8;
  for (int i = tid; i < 1024; i += 256)
    q8[i >> 7][i & 127] = query[(size_t)(b0 + (i >> 7)) * 128 + (i & 127)];
  __syncthreads();
  int h = tid;
  const float4* w0 = (const float4*)(W1 + (size_t)h * 512);
  const float4* w1 = (const float4*)(W1 + (size_t)h * 512 + 256);
  float acc[8];
  float bb = b1[h];
#pragma unroll
  for (int i = 0; i < 8; ++i) acc[i] = bb;
  for (int d4 = 0; d4 < 32; ++d4) {
    float4 wa = w0[d4], wb = w1[d4];
    float wv0 = wa.x + wb.x, wv1 = wa.y + wb.y, wv2 = wa.z + wb.z, wv3 = wa.w + wb.w;
#pragma unroll
    for (int i = 0; i < 8; ++i) {
      float4 qv = ((const float4*)q8[i])[d4];
      acc[i] += wv0 * qv.x + wv1 * qv.y + wv2 * qv.z + wv3 * qv.w;
    }
  }
#pragma unroll
  for (int i = 0; i < 8; ++i) U[(size_t)(b0 + i) * 256 + h] = acc[i];
}

// ---------------- fused main: block = b, 4 waves, 32-l tiles, pipelined ------
// R15: 7 phases of 32 l (vs 13 of 16) — 64 MFMA/wave/phase between barriers,
// testing whether the ~4.8k cy/phase overhead is per-phase-constant.
// Same 1-bar hazard invariants as R14.
__global__ __launch_bounds__(256, 2) void din_fused(
    const float* __restrict__ query, const float* __restrict__ keys,
    const int* __restrict__ mask,
    const float* __restrict__ b2p, const float* __restrict__ a1p,
    const float* __restrict__ a2p, const float* __restrict__ W3,
    const float* __restrict__ U, const short* __restrict__ Wk,
    const short* __restrict__ Wd, const short* __restrict__ W2b,
    float* __restrict__ out) {
  __shared__ short Kt[2][32 * 128];   // 16 KB streaming key tiles, XOR-swizzled
  __shared__ short H1[2][32 * 256];   // 32 KB h1 tiles, XOR-swizzled
  __shared__ float wred[4][224];      // 3.5 KB per-wave score partials
  __shared__ float Ul[256];
  __shared__ float b2l[128];
  __shared__ float w3l[128];
  __shared__ float wl[208];
  __shared__ float red[8];
  __shared__ float opart[8][128];

  const int tid = threadIdx.x;
  const int b = blockIdx.x;
  const int lane = tid & 63, wid = tid >> 6;  // 4 waves
  const int lr = lane & 15, lg = lane >> 4;

  const float a1 = a1p[0], a2 = a2p[0];

  Ul[tid] = U[(size_t)b * 256 + tid];
  if (tid < 128) { b2l[tid] = b2p[tid]; w3l[tid] = W3[tid]; }

  // ---- persistent fragments ----
  bf16x8 mf[4][4];   // GEMM1 A: M_b, wave owns 64 h
  {
    const float* qrow = query + (size_t)b * 128;
#pragma unroll
    for (int nt = 0; nt < 4; ++nt) {
      int h = wid * 64 + nt * 16 + lr;
#pragma unroll
      for (int ks = 0; ks < 4; ++ks) {
        int d0 = ks * 32 + lg * 8;
        bf16x8 wk = *(const bf16x8*)(Wk + h * 128 + d0);
        bf16x8 wd = *(const bf16x8*)(Wd + h * 128 + d0);
        float4 q0 = *(const float4*)(qrow + d0);
        float4 q1 = *(const float4*)(qrow + d0 + 4);
        float qv[8] = {q0.x, q0.y, q0.z, q0.w, q1.x, q1.y, q1.z, q1.w};
        float mv[8];
#pragma unroll
        for (int j = 0; j < 8; ++j) mv[j] = b2f(wk[j]) + b2f(wd[j]) * qv[j];
        union { bf16x8 v; uint32_t u[4]; } mm;
#pragma unroll
        for (int j = 0; j < 4; ++j) mm.u[j] = pk2(mv[2 * j], mv[2 * j + 1]);
        mf[nt][ks] = mm.v;
      }
    }
  }
  bf16x8 w2f[2][8];  // GEMM2 A: W2, wave owns 32 g
#pragma unroll
  for (int nt2 = 0; nt2 < 2; ++nt2) {
    int g = wid * 32 + nt2 * 16 + lr;
#pragma unroll
    for (int ks = 0; ks < 8; ++ks)
      w2f[nt2][ks] = *(const bf16x8*)(W2b + g * 256 + ks * 32 + lg * 8);
  }

  // staging geometry: 32 rows/tile, 8 thr/row, 16 floats (64B) per thread
  const int srow = tid >> 3;          // 0..31
  const int scol = (tid & 7) * 16;    // 0..112 (shorts/floats)
  const int ssw = (srow & 7) << 3;

  // ring hold: tile t+1 (4 float4 = 16 VGPR)
  float4 r0, r1, r2, r3;
  {
    // tile 0 staged direct (rows 0..31 valid)
    const float4* kp4 = (const float4*)(keys + ((size_t)b * 200 + srow) * 128 + scol);
    float4 x0 = kp4[0], x1 = kp4[1], x2 = kp4[2], x3 = kp4[3];
    union { bf16x8 v; uint32_t u[4]; } w0, w1;
    w0.u[0] = pk2(x0.x, x0.y); w0.u[1] = pk2(x0.z, x0.w);
    w0.u[2] = pk2(x1.x, x1.y); w0.u[3] = pk2(x1.z, x1.w);
    w1.u[0] = pk2(x2.x, x2.y); w1.u[1] = pk2(x2.z, x2.w);
    w1.u[2] = pk2(x3.x, x3.y); w1.u[3] = pk2(x3.z, x3.w);
    *(bf16x8*)(&Kt[0][srow * 128 + (scol ^ ssw)]) = w0.v;
    *(bf16x8*)(&Kt[0][srow * 128 + ((scol + 8) ^ ssw)]) = w1.v;
    // tile 1 into ring (rows 32..63 valid)
    const float4* kp4b = (const float4*)(keys + ((size_t)b * 200 + 32 + srow) * 128 + scol);
    r0 = kp4b[0]; r1 = kp4b[1]; r2 = kp4b[2]; r3 = kp4b[3];
  }
  bar();

  const int sw = (lr & 7) << 3;

  // ---- 7 pipelined phases of 32 l, 1 barrier each ----
  for (int t = 0; t < 7; ++t) {
    const int buf = t & 1;

    // issue loads for tile t+2 (survive bar(); written next phase)
    float4 n0, n1, n2, n3;
    if (t < 5) {
      int gl = (t + 2) * 32 + srow;
      n0 = n1 = n2 = n3 = make_float4(0.f, 0.f, 0.f, 0.f);
      if (gl < 200) {
        const float4* kp4 = (const float4*)(keys + ((size_t)b * 200 + gl) * 128 + scol);
        n0 = kp4[0]; n1 = kp4[1]; n2 = kp4[2]; n3 = kp4[3];
      }
    }

    // ---- GEMM2 on tile t-1 (reads H1[buf^1]) ----
    if (t >= 1) {
      const short* h1p = H1[buf ^ 1];
#pragma unroll
      for (int s = 0; s < 2; ++s) {
        const short* hr = &h1p[(s * 16 + lr) * 256];
        f32x4 acc2[2];
#pragma unroll
        for (int nt2 = 0; nt2 < 2; ++nt2)
#pragma unroll
          for (int r = 0; r < 4; ++r) acc2[nt2][r] = b2l[wid * 32 + nt2 * 16 + lg * 4 + r];
        __builtin_amdgcn_s_setprio(1);
#pragma unroll
        for (int ks = 0; ks < 8; ++ks) {
          bf16x8 hf = *(const bf16x8*)(&hr[(ks * 32 + lg * 8) ^ sw]);
          acc2[0] = __builtin_amdgcn_mfma_f32_16x16x32_bf16(w2f[0][ks], hf, acc2[0], 0, 0, 0);
          acc2[1] = __builtin_amdgcn_mfma_f32_16x16x32_bf16(w2f[1][ks], hf, acc2[1], 0, 0, 0);
        }
        __builtin_amdgcn_s_setprio(0);
        float sred = 0.f;
#pragma unroll
        for (int nt2 = 0; nt2 < 2; ++nt2)
#pragma unroll
          for (int r = 0; r < 4; ++r) {
            float v = acc2[nt2][r];
            v = (v >= 0.f) ? v : a2 * v;
            sred += v * w3l[wid * 32 + nt2 * 16 + lg * 4 + r];
          }
        sred += __shfl_xor(sred, 16);
        sred += __shfl_xor(sred, 32);
        if (lg == 0) wred[wid][(t - 1) * 32 + s * 16 + lr] = sred;
      }
    }

    // ---- GEMM1 on tile t (reads Kt[buf], writes H1[buf]) ----
    {
      short* h1b = H1[buf];
#pragma unroll
      for (int s = 0; s < 2; ++s) {
        const int lrow = s * 16 + lr;
        bf16x8 kf[4];
#pragma unroll
        for (int ks = 0; ks < 4; ++ks)
          kf[ks] = *(const bf16x8*)(&Kt[buf][lrow * 128 + ((ks * 32 + lg * 8) ^ sw)]);
        f32x4 acc[4];
#pragma unroll
        for (int nt = 0; nt < 4; ++nt)
#pragma unroll
          for (int r = 0; r < 4; ++r) acc[nt][r] = Ul[wid * 64 + nt * 16 + lg * 4 + r];
        __builtin_amdgcn_s_setprio(1);
#pragma unroll
        for (int ks = 0; ks < 4; ++ks)
#pragma unroll
          for (int nt = 0; nt < 4; ++nt)
            acc[nt] = __builtin_amdgcn_mfma_f32_16x16x32_bf16(mf[nt][ks], kf[ks], acc[nt], 0, 0, 0);
        __builtin_amdgcn_s_setprio(0);
#pragma unroll
        for (int nt = 0; nt < 4; ++nt) {
          float v0 = acc[nt][0], v1 = acc[nt][1], v2 = acc[nt][2], v3 = acc[nt][3];
          v0 = (v0 >= 0.f) ? v0 : a1 * v0;
          v1 = (v1 >= 0.f) ? v1 : a1 * v1;
          v2 = (v2 >= 0.f) ? v2 : a1 * v2;
          v3 = (v3 >= 0.f) ? v3 : a1 * v3;
          union { bf16x4 v; uint32_t u[2]; } hh;
          hh.u[0] = pk2(v0, v1); hh.u[1] = pk2(v2, v3);
          int h0 = wid * 64 + nt * 16 + lg * 4;
          *(bf16x4*)(&h1b[lrow * 256 + (h0 ^ sw)]) = hh.v;
        }
      }
    }

    // ring write: tile t+1 -> Kt[buf^1]
    if (t < 6) {
      union { bf16x8 v; uint32_t u[4]; } w0, w1;
      w0.u[0] = pk2(r0.x, r0.y); w0.u[1] = pk2(r0.z, r0.w);
      w0.u[2] = pk2(r1.x, r1.y); w0.u[3] = pk2(r1.z, r1.w);
      w1.u[0] = pk2(r2.x, r2.y); w1.u[1] = pk2(r2.z, r2.w);
      w1.u[2] = pk2(r3.x, r3.y); w1.u[3] = pk2(r3.z, r3.w);
      *(bf16x8*)(&Kt[buf ^ 1][srow * 128 + (scol ^ ssw)]) = w0.v;
      *(bf16x8*)(&Kt[buf ^ 1][srow * 128 + ((scol + 8) ^ ssw)]) = w1.v;
    }
    if (t < 5) { r0 = n0; r1 = n1; r2 = n2; r3 = n3; }

    bar();  // the ONLY barrier per phase
  }

  // ---- drain: GEMM2 on tile 6 (H1[0]) ----
  {
    const short* h1p = H1[0];
#pragma unroll
    for (int s = 0; s < 2; ++s) {
      const short* hr = &h1p[(s * 16 + lr) * 256];
      f32x4 acc2[2];
#pragma unroll
      for (int nt2 = 0; nt2 < 2; ++nt2)
#pragma unroll
        for (int r = 0; r < 4; ++r) acc2[nt2][r] = b2l[wid * 32 + nt2 * 16 + lg * 4 + r];
#pragma unroll
      for (int ks = 0; ks < 8; ++ks) {
        bf16x8 hf = *(const bf16x8*)(&hr[(ks * 32 + lg * 8) ^ sw]);
        acc2[0] = __builtin_amdgcn_mfma_f32_16x16x32_bf16(w2f[0][ks], hf, acc2[0], 0, 0, 0);
        acc2[1] = __builtin_amdgcn_mfma_f32_16x16x32_bf16(w2f[1][ks], hf, acc2[1], 0, 0, 0);
      }
      float sred = 0.f;
#pragma unroll
      for (int nt2 = 0; nt2 < 2; ++nt2)
#pragma unroll
        for (int r = 0; r < 4; ++r) {
          float v = acc2[nt2][r];
          v = (v >= 0.f) ? v : a2 * v;
          sred += v * w3l[wid * 32 + nt2 * 16 + lg * 4 + r];
        }
      sred += __shfl_xor(sred, 16);
      sred += __shfl_xor(sred, 32);
      if (lg == 0) wred[wid][6 * 32 + s * 16 + lr] = sred;
    }
  }
  bar();

  // ---- masked softmax over l=0..199 ----
  float val = NEGV;
  int mk = 0;
  if (tid < 200) {
    mk = mask[(size_t)b * 200 + tid];
    float sc = wred[0][tid] + wred[1][tid] + wred[2][tid] + wred[3][tid];
    val = mk ? sc : NEGV;
  }
  float m = val;
#pragma unroll
  for (int off = 1; off < 64; off <<= 1) m = fmaxf(m, __shfl_xor(m, off));
  if (lane == 0) red[wid] = m;
  bar();
  float smax = fmaxf(fmaxf(red[0], red[1]), fmaxf(red[2], red[3]));
  float pex = (tid < 200 && mk) ? __expf(val - smax) : 0.f;
  float s = pex;
#pragma unroll
  for (int off = 1; off < 64; off <<= 1) s += __shfl_xor(s, off);
  if (lane == 0) red[4 + wid] = s;
  bar();
  float ssum = red[4] + red[5] + red[6] + red[7];
  float winv = (ssum > 0.f) ? 1.f / ssum : 0.f;
  if (tid < 208) wl[tid] = (tid < 200) ? pex * winv : 0.f;
  bar();

  // ---- weighted sum from global keys (L3-hot) ----
  {
    const int d4 = (tid & 31) << 2;  // 0..124
    const int slice = tid >> 5;      // 0..7
    float ax = 0.f, ay = 0.f, az = 0.f, aw = 0.f;
    for (int l = slice; l < 200; l += 8) {
      float wv = wl[l];
      float4 kv = *(const float4*)(keys + ((size_t)b * 200 + l) * 128 + d4);
      ax += wv * kv.x; ay += wv * kv.y; az += wv * kv.z; aw += wv * kv.w;
    }
    *(float4*)(&opart[slice][d4]) = make_float4(ax, ay, az, aw);
  }
  __syncthreads();
  if (tid < 128) {
    float acc = 0.f;
#pragma unroll
    for (int i = 0; i < 8; ++i) acc += opart[i][tid];
    out[(size_t)b * 128 + tid] = acc;
  }
}

extern "C" void kernel_launch(void* const* d_in, const int* in_sizes, int n_in,
                              void* d_out, int out_size, void* d_ws, size_t ws_size,
                              hipStream_t stream) {
  const float* query = (const float*)d_in[0];
  const float* keys  = (const float*)d_in[1];
  const int*   maskp = (const int*)d_in[2];
  const float* W1    = (const float*)d_in[3];
  const float* b1    = (const float*)d_in[4];
  const float* a1    = (const float*)d_in[5];
  const float* W2    = (const float*)d_in[6];
  const float* b2    = (const float*)d_in[7];
  const float* a2    = (const float*)d_in[8];
  const float* W3    = (const float*)d_in[9];
  float* out = (float*)d_out;

  float* U   = (float*)d_ws;                         // 2 MiB
  short* Wk  = (short*)((char*)d_ws + 2097152);      // 64 KiB
  short* Wd  = Wk + 32768;                           // 64 KiB
  short* W2b = Wd + 32768;                           // 64 KiB

  prep_weights<<<384, 256, 0, stream>>>(W1, W2, Wk, Wd, W2b);
  prep_u<<<256, 256, 0, stream>>>(query, W1, b1, U);
  din_fused<<<2048, 256, 0, stream>>>(query, keys, maskp, b2, a1, a2, W3,
                                      U, Wk, Wd, W2b, out);
}